// Round 9
// baseline (45.840 us; speedup 1.0000x reference)
//
#include <hip/hip_runtime.h>

// Conv2D 3x3 pad=1: x (32,64,64,64) f32 NCHW, w (128,64,3,3) OIHW, bias(128), out (32,128,64,64) f32.
// Persistent-tile implicit GEMM, zero vmcnt-drains in the K-loop:
//   prep_xp: NCHW f32 -> padded+granule-swizzled xP[n][66][66][64ci] bf16 (borders zero)
//   prep_wS: OIHW f32 -> wS[co][p][slot] bf16 with A-side XOR pre-applied
//   conv_mfma9: grid 256 (1/CU), 512 thr = 8 waves (2 co-half x 4 h-row).
//     Block: 64co x 16h x 64w as 4 iters of 4h. W (all 9 planes, 73.7KB) staged ONCE
//     via gload_lds; X rolls through a 6-row circular window (50.7KB): issue next-4-row
//     reg loads early, compute 18 steps {6 ds_read_b128 + 8 MFMA} with no vmem waits,
//     async stores, raw s_barrier, write-late ds_write, lgkmcnt(0)+s_barrier.

typedef short short8 __attribute__((ext_vector_type(8)));
typedef float f32x4  __attribute__((ext_vector_type(4)));

static __device__ __forceinline__ unsigned short f2bf(float f) {
    unsigned int u = __float_as_uint(f);
    u = (u + 0x7FFFu + ((u >> 16) & 1u)) >> 16;   // RNE
    return (unsigned short)u;
}
static __device__ __forceinline__ unsigned int pk2(float lo, float hi) {
    return (unsigned int)f2bf(lo) | ((unsigned int)f2bf(hi) << 16);
}
static __device__ __forceinline__ void gload16(const void* g, void* l) {
    __builtin_amdgcn_global_load_lds(
        (const __attribute__((address_space(1))) void*)g,
        (__attribute__((address_space(3))) void*)l, 16, 0, 0);
}

// ---- prep_xp: x[n][ci][h][w] f32 -> xP[n][h'][w'][ci] bf16, padded (66x66), granule-swizzled ----
__global__ __launch_bounds__(256)
void prep_xp(const float* __restrict__ x, unsigned short* __restrict__ xP)
{
    const int hp = blockIdx.x, n = blockIdx.y, tid = threadIdx.x;
    unsigned short* rowBase = xP + (((size_t)n * 66 + hp) * 66) * 64;
    if (hp == 0 || hp == 65) {                    // zero border row
        uint4 z; z.x = z.y = z.z = z.w = 0u;
        for (int i = tid; i < 528; i += 256) ((uint4*)rowBase)[i] = z;
        return;
    }
    __shared__ float T[64][65];
    const int h = hp - 1;
    const size_t nbase = (size_t)n * 262144 + (size_t)h * 64;
    #pragma unroll
    for (int i = 0; i < 16; ++i) {
        int idx = tid + i * 256;                  // ci*64 + w
        int ci = idx >> 6, w = idx & 63;
        T[ci][w] = x[nbase + (size_t)ci * 4096 + w];
    }
    __syncthreads();
    if (tid < 16) {                               // zero border cols w'=0 and w'=65
        uint4 z; z.x = z.y = z.z = z.w = 0u;
        int wp = (tid >> 3) * 65;
        ((uint4*)(rowBase + wp * 64))[tid & 7] = z;
    }
    const int w = tid >> 2, cg = tid & 3;
    const int wp = w + 1;
    #pragma unroll
    for (int t = 0; t < 2; ++t) {
        const int g = cg * 2 + t;
        uint4 v;
        v.x = pk2(T[g*8+0][w], T[g*8+1][w]);
        v.y = pk2(T[g*8+2][w], T[g*8+3][w]);
        v.z = pk2(T[g*8+4][w], T[g*8+5][w]);
        v.w = pk2(T[g*8+6][w], T[g*8+7][w]);
        *(uint4*)(rowBase + wp * 64 + ((g ^ (wp & 7)) * 8)) = v;
    }
}

// ---- prep_wS: w[co][ci][3][3] f32 -> wS[(co*9+p)*8+slot] (16B granules), slot holds granule slot^(co&7) ----
__global__ __launch_bounds__(256)
void prep_wS(const float* __restrict__ w, unsigned short* __restrict__ wS)
{
    int t = blockIdx.x * 256 + threadIdx.x;       // granule id
    if (t >= 9216) return;
    int gp = t & 7, p = (t >> 3) % 9, co = (t >> 3) / 9;
    int g = gp ^ (co & 7);
    uint4 v;
    const float* src = w + (size_t)(co * 64 + g * 8) * 9 + p;
    v.x = pk2(src[0*9], src[1*9]);
    v.y = pk2(src[2*9], src[3*9]);
    v.z = pk2(src[4*9], src[5*9]);
    v.w = pk2(src[6*9], src[7*9]);
    *(uint4*)(wS + (size_t)t * 8) = v;
}

// ---------------- main persistent MFMA conv ----------------
#define XROWB 8448                   // 66 wp * 64 ci * 2B per padded row
#define WOFF  50688                  // X window: 6 rows * 8448
#define TOTAL_LDS (50688 + 73728)    // 124416 B

__global__ __launch_bounds__(512, 2)
void conv_mfma9(const unsigned short* __restrict__ xP,
                const unsigned short* __restrict__ wS,
                const float* __restrict__ bias,
                float* __restrict__ out)
{
    extern __shared__ __align__(16) char lds[];

    const int tid = threadIdx.x;
    const int bid = blockIdx.x;                   // 256 blocks
    const int n   = bid >> 3;
    const int cb  = (bid >> 2) & 1;               // co half
    const int hq  = bid & 3;                      // 16-h quarter
    const int wid = tid >> 6, lane = tid & 63;
    const int wm  = wid >> 2;                     // 0..1: 32-co half within cb
    const int wn  = wid & 3;                      // 0..3: h row within 4h iter
    const int l15 = lane & 15, l4 = lane >> 4;
    const int widoff = wid * 1024;

    const unsigned short* xPn = xP + (size_t)n * (66 * 66 * 64);
    const int hbase = hq * 16;

    // ---- prologue: W (all 9 planes, 64co half) once + X rows hbase..hbase+5 ----
    #pragma unroll
    for (int k = 0; k < 9; ++k) {
        const int Gw = tid + k * 512;
        const int slot = Gw & 7, col = (Gw >> 3) & 63, p = Gw >> 9;
        gload16(wS + ((((size_t)(cb * 64 + col) * 9 + p) * 8 + slot) << 3),
                lds + WOFF + k * 8192 + widoff);
    }
    #pragma unroll
    for (int rr = 0; rr < 6; ++rr) {
        const int hp = hbase + rr;
        const int slot = hp % 6;
        const unsigned short* srcRow = xPn + (size_t)hp * 4224;
        gload16(srcRow + tid * 8, lds + slot * XROWB + widoff);
        if (tid < 16)
            gload16(srcRow + (512 + tid) * 8, lds + slot * XROWB + 8192);
    }
    __syncthreads();   // prologue drain (once)

    #pragma unroll
    for (int it = 0; it < 4; ++it) {
        const int h0 = hbase + it * 4;

        // ---- (A) issue next-iter row loads to regs (rows hp = h0+6 .. h0+9) ----
        uint4 xr[4]; uint4 xtail;
        if (it < 3) {
            #pragma unroll
            for (int rr = 0; rr < 4; ++rr)
                xr[rr] = *(const uint4*)(xPn + (size_t)(h0 + 6 + rr) * 4224 + tid * 8);
            if (tid < 64)
                xtail = *(const uint4*)(xPn + (size_t)(h0 + 6 + (tid >> 4)) * 4224 +
                                        (512 + (tid & 15)) * 8);
        }

        f32x4 acc[2][4];
        #pragma unroll
        for (int mf = 0; mf < 2; ++mf)
            #pragma unroll
            for (int nf = 0; nf < 4; ++nf)
                acc[mf][nf] = (f32x4)0.0f;

        // ---- (B) K-loop: 9 planes x 2 c, all operands from LDS, no vmem waits ----
        #pragma unroll
        for (int p = 0; p < 9; ++p) {
            const int kh = p / 3, kw = p - kh * 3;
            const int rowslot = (h0 + wn + kh) % 6;
            const char* xrow = lds + rowslot * XROWB;
            const char* wpl  = lds + WOFF + p * 8192;
            #pragma unroll
            for (int c = 0; c < 2; ++c) {
                short8 Af[2], Bf[4];
                #pragma unroll
                for (int mf = 0; mf < 2; ++mf) {
                    const int col = wm * 32 + mf * 16 + l15;
                    Af[mf] = *(const short8*)(wpl + col * 128 +
                                              (((c * 4 + l4) ^ (col & 7)) * 16));
                }
                #pragma unroll
                for (int nf = 0; nf < 4; ++nf) {
                    const int wp = nf * 16 + l15 + kw;
                    Bf[nf] = *(const short8*)(xrow + wp * 128 +
                                              (((c * 4 + l4) ^ (wp & 7)) * 16));
                }
                __builtin_amdgcn_s_setprio(1);
                #pragma unroll
                for (int mf = 0; mf < 2; ++mf)
                    #pragma unroll
                    for (int nf = 0; nf < 4; ++nf)
                        acc[mf][nf] = __builtin_amdgcn_mfma_f32_16x16x32_bf16(
                            Af[mf], Bf[nf], acc[mf][nf], 0, 0, 0);
                __builtin_amdgcn_s_setprio(0);
            }
        }

        // ---- (C) bias + async stores ----
        {
            const int h = h0 + wn;
            #pragma unroll
            for (int mf = 0; mf < 2; ++mf) {
                const f32x4 bv4 = *(const f32x4*)(bias + cb * 64 + wm * 32 + mf * 16 + l4 * 4);
                #pragma unroll
                for (int r = 0; r < 4; ++r) {
                    const int co = cb * 64 + wm * 32 + mf * 16 + l4 * 4 + r;
                    float* orow = out + (((size_t)n * 128 + co) * 64 + h) * 64;
                    #pragma unroll
                    for (int nf = 0; nf < 4; ++nf)
                        orow[nf * 16 + l15] = acc[mf][nf][r] + bv4[r];
                }
            }
        }

        // ---- (D/E/F) rotate window: barrier, write-late, barrier. No vmcnt(0). ----
        if (it < 3) {
            __builtin_amdgcn_sched_barrier(0);
            __builtin_amdgcn_s_barrier();                 // all waves done reading window
            __builtin_amdgcn_sched_barrier(0);
            #pragma unroll
            for (int rr = 0; rr < 4; ++rr) {
                const int slot = (h0 + 6 + rr) % 6;
                *(uint4*)(lds + slot * XROWB + tid * 16) = xr[rr];
            }
            if (tid < 64) {
                const int slot = (h0 + 6 + (tid >> 4)) % 6;
                *(uint4*)(lds + slot * XROWB + (512 + (tid & 15)) * 16) = xtail;
            }
            __builtin_amdgcn_sched_barrier(0);
            asm volatile("s_waitcnt lgkmcnt(0)" ::: "memory");
            __builtin_amdgcn_s_barrier();                 // new rows visible
            __builtin_amdgcn_sched_barrier(0);
        }
    }
}

// ---------------- fp32 fallback if ws too small ----------------
__global__ __launch_bounds__(256, 4)
void conv2d_f32_tiled(const float* __restrict__ x,
                      const float* __restrict__ wgt,
                      const float* __restrict__ bias,
                      float* __restrict__ out)
{
    __shared__ float Xlds[8][10][66];
    __shared__ float Wlds[32][72];
    const int tid = threadIdx.x;
    const int co0 = blockIdx.x * 32, h0 = blockIdx.y * 8, n = blockIdx.z;
    const int tco = tid >> 6, lane = tid & 63;
    float acc[8][8];
    #pragma unroll
    for (int i = 0; i < 8; ++i)
        #pragma unroll
        for (int j = 0; j < 8; ++j) acc[i][j] = 0.0f;
    for (int cc = 0; cc < 8; ++cc) {
        const int ci0 = cc * 8;
        for (int idx = tid; idx < 8 * 10 * 66; idx += 256) {
            const int ww = idx % 66, t = idx / 66, hh = t % 10, ci = t / 10;
            const int gh = h0 + hh - 1, gw = ww - 1;
            float v = 0.0f;
            if ((unsigned)gh < 64u && (unsigned)gw < 64u)
                v = x[(((size_t)n * 64 + ci0 + ci) * 64 + gh) * 64 + gw];
            Xlds[ci][hh][ww] = v;
        }
        for (int idx = tid; idx < 32 * 72; idx += 256) {
            const int r = idx % 72, co = idx / 72;
            Wlds[co][r] = wgt[(size_t)(co0 + co) * 576 + ci0 * 9 + r];
        }
        __syncthreads();
        for (int ci = 0; ci < 8; ++ci)
            #pragma unroll
            for (int kh = 0; kh < 3; ++kh)
                #pragma unroll
                for (int kw = 0; kw < 3; ++kw) {
                    float wv[8];
                    #pragma unroll
                    for (int i = 0; i < 8; ++i) wv[i] = Wlds[tco * 8 + i][ci * 9 + kh * 3 + kw];
                    #pragma unroll
                    for (int j = 0; j < 8; ++j) {
                        const float xv = Xlds[ci][j + kh][lane + kw];
                        #pragma unroll
                        for (int i = 0; i < 8; ++i) acc[i][j] = fmaf(wv[i], xv, acc[i][j]);
                    }
                }
        __syncthreads();
    }
    #pragma unroll
    for (int i = 0; i < 8; ++i) {
        const int co = co0 + tco * 8 + i;
        const float b = bias[co];
        #pragma unroll
        for (int j = 0; j < 8; ++j)
            out[(((size_t)n * 128 + co) * 64 + (h0 + j)) * 64 + lane] = acc[i][j] + b;
    }
}

extern "C" void kernel_launch(void* const* d_in, const int* in_sizes, int n_in,
                              void* d_out, int out_size, void* d_ws, size_t ws_size,
                              hipStream_t stream)
{
    const float* x    = (const float*)d_in[0];
    const float* wgt  = (const float*)d_in[1];
    const float* bias = (const float*)d_in[2];
    float* out        = (float*)d_out;

    const size_t XP_BYTES = (size_t)32 * 66 * 66 * 64 * 2;   // 17,842,176
    const size_t WS_BYTES = (size_t)9216 * 16;               //    147,456

    if (ws_size < XP_BYTES + WS_BYTES) {
        dim3 grid(4, 8, 32);
        conv2d_f32_tiled<<<grid, 256, 0, stream>>>(x, wgt, bias, out);
        return;
    }

    unsigned short* xP = (unsigned short*)d_ws;
    unsigned short* wS = (unsigned short*)((char*)d_ws + XP_BYTES);

    (void)hipFuncSetAttribute((const void*)conv_mfma9,
                              hipFuncAttributeMaxDynamicSharedMemorySize, TOTAL_LDS);

    prep_xp<<<dim3(66, 32), 256, 0, stream>>>(x, xP);
    prep_wS<<<dim3(36), 256, 0, stream>>>(wgt, wS);
    conv_mfma9<<<dim3(256), 512, TOTAL_LDS, stream>>>(xP, wS, bias, out);
}